// Round 2
// baseline (946.840 us; speedup 1.0000x reference)
//
#include <hip/hip_runtime.h>

typedef __attribute__((ext_vector_type(8))) short short8;
typedef __attribute__((ext_vector_type(4))) float f32x4;
typedef __attribute__((ext_vector_type(4))) int int4v;
typedef __attribute__((ext_vector_type(4))) unsigned short ushort4v;

#define SCALE_F 0.0625f   // C^-0.5 = 256^-0.5
#define EPS_F 1e-5f

__device__ __forceinline__ float bf2f(unsigned short u) {
  unsigned int i = ((unsigned int)u) << 16;
  return __builtin_bit_cast(float, i);
}
__device__ __forceinline__ unsigned short f2bf(float f) {
  unsigned int i = __builtin_bit_cast(unsigned int, f);
  i += 0x7fffu + ((i >> 16) & 1u);
  return (unsigned short)(i >> 16);
}

// ---- cast weight [K,N] f32 -> [N,K] bf16 (transposed) ----
template<int K, int N>
__global__ void cast_wt(const float* __restrict__ src, unsigned short* __restrict__ dst) {
  int id = blockIdx.x * 256 + threadIdx.x;          // id = n*K + k
  if (id >= K * N) return;
  int k = id % K, n = id / K;
  dst[id] = f2bf(src[(size_t)k * N + n]);
}

// ---- precompute relative-position bias [head][i][j] ----
__global__ void build_relb(const float* __restrict__ table, float* __restrict__ relb) {
  int id = blockIdx.x * 256 + threadIdx.x;          // 8*64*64
  int h = id >> 12, i = (id >> 6) & 63, j = id & 63;
  int dy = (i >> 3) - (j >> 3) + 7;
  int dx = (i & 7) - (j & 7) + 7;
  relb[id] = table[(dy * 15 + dx) * 8 + h];
}

// ---- window partition + LN1: x[B,C,64,64] -> h bf16 [M,256] ----
__global__ __launch_bounds__(256) void part_ln1(
    const float* __restrict__ x, const float* __restrict__ g, const float* __restrict__ bb,
    unsigned short* __restrict__ h) {
  int m = blockIdx.x * 4 + (threadIdx.x >> 6);
  int l = threadIdx.x & 63;
  int b = m >> 12, gg = (m >> 6) & 63, s = m & 63;
  int sp = ((gg >> 3) * 8 + (s >> 3)) * 64 + (gg & 7) * 8 + (s & 7);
  const float* xp = x + (size_t)b * 256 * 4096 + sp;
  float v[4];
  float sum = 0.f, ss = 0.f;
#pragma unroll
  for (int j = 0; j < 4; j++) {
    v[j] = xp[(size_t)(l * 4 + j) * 4096];
    sum += v[j]; ss += v[j] * v[j];
  }
#pragma unroll
  for (int d = 1; d < 64; d <<= 1) {
    sum += __shfl_xor(sum, d, 64);
    ss  += __shfl_xor(ss, d, 64);
  }
  float mu = sum * (1.f / 256.f);
  float var = ss * (1.f / 256.f) - mu * mu;
  float rs = rsqrtf(var + EPS_F);
  ushort4v oh;
#pragma unroll
  for (int j = 0; j < 4; j++) {
    int c = l * 4 + j;
    oh[j] = f2bf((v[j] - mu) * rs * g[c] + bb[c]);
  }
  *(ushort4v*)(h + (size_t)m * 256 + l * 4) = oh;
}

// ---- LN2: x2 bf16 [M,256] -> h2 bf16 [M,256] ----
__global__ __launch_bounds__(256) void ln2k(
    const unsigned short* __restrict__ x2, const float* __restrict__ g, const float* __restrict__ bb,
    unsigned short* __restrict__ h2) {
  int m = blockIdx.x * 4 + (threadIdx.x >> 6);
  int l = threadIdx.x & 63;
  ushort4v u = *(const ushort4v*)(x2 + (size_t)m * 256 + l * 4);
  float v[4];
  float sum = 0.f, ss = 0.f;
#pragma unroll
  for (int j = 0; j < 4; j++) { v[j] = bf2f(u[j]); sum += v[j]; ss += v[j] * v[j]; }
#pragma unroll
  for (int d = 1; d < 64; d <<= 1) {
    sum += __shfl_xor(sum, d, 64);
    ss  += __shfl_xor(ss, d, 64);
  }
  float mu = sum * (1.f / 256.f);
  float var = ss * (1.f / 256.f) - mu * mu;
  float rs = rsqrtf(var + EPS_F);
  ushort4v oh;
#pragma unroll
  for (int j = 0; j < 4; j++) {
    int c = l * 4 + j;
    oh[j] = f2bf((v[j] - mu) * rs * g[c] + bb[c]);
  }
  *(ushort4v*)(h2 + (size_t)m * 256 + l * 4) = oh;
}

// ---- GEMM: A bf16 [rows,K] x Bt bf16 [N,K] -> out, 128x128 tile, 4 waves ----
// EPI_QKV:   out bf16 [rows,N] (chunk-local)
// EPI_MERGE: out bf16 x2[Mglobal,256], res = x f32 [B,C,64,64] gathered
// EPI_GELU:  out bf16 [rows,N] (chunk-local)
// EPI_OUT:   out f32 d_out scatter, res = x2 bf16 [Mglobal,256]
enum { EPI_QKV = 0, EPI_MERGE = 1, EPI_GELU = 2, EPI_OUT = 3 };

template<int EPI>
__global__ __launch_bounds__(256) void gemm_bt(
    const unsigned short* __restrict__ A, const unsigned short* __restrict__ Bt,
    const float* __restrict__ bias, const void* __restrict__ res,
    void* __restrict__ out, int K, int N, long m_base) {
  __shared__ __align__(16) unsigned short As[128 * 72];
  __shared__ __align__(16) unsigned short Bs[128 * 72];
  const int tid = threadIdx.x;
  const int l15 = tid & 15, lhi = (tid & 63) >> 4;
  const int wid = tid >> 6, wm = wid >> 1, wn = wid & 1;
  const size_t m0 = (size_t)blockIdx.x * 128;
  const int n0 = blockIdx.y * 128;

  f32x4 acc[4][4];
#pragma unroll
  for (int i = 0; i < 4; i++)
#pragma unroll
    for (int j = 0; j < 4; j++) acc[i][j] = (f32x4){0.f, 0.f, 0.f, 0.f};

  for (int k0 = 0; k0 < K; k0 += 64) {
    __syncthreads();
#pragma unroll
    for (int i = 0; i < 4; i++) {
      int cid = i * 256 + tid;
      int row = cid >> 3, kc = cid & 7;
      int4v va = *(const int4v*)(A + (m0 + row) * (size_t)K + k0 + kc * 8);
      *(int4v*)(&As[row * 72 + kc * 8]) = va;
      int4v vb = *(const int4v*)(Bt + (size_t)(n0 + row) * (size_t)K + k0 + kc * 8);
      *(int4v*)(&Bs[row * 72 + kc * 8]) = vb;
    }
    __syncthreads();
#pragma unroll
    for (int ks = 0; ks < 2; ks++) {
      short8 af[4], bfr[4];
#pragma unroll
      for (int t = 0; t < 4; t++) {
        af[t]  = *(const short8*)(&As[(wm * 64 + t * 16 + l15) * 72 + ks * 32 + lhi * 8]);
        bfr[t] = *(const short8*)(&Bs[(wn * 64 + t * 16 + l15) * 72 + ks * 32 + lhi * 8]);
      }
#pragma unroll
      for (int mt = 0; mt < 4; mt++)
#pragma unroll
        for (int nt = 0; nt < 4; nt++)
          acc[mt][nt] = __builtin_amdgcn_mfma_f32_16x16x32_bf16(af[mt], bfr[nt], acc[mt][nt], 0, 0, 0);
    }
  }

#pragma unroll
  for (int mt = 0; mt < 4; mt++) {
#pragma unroll
    for (int nt = 0; nt < 4; nt++) {
#pragma unroll
      for (int r = 0; r < 4; r++) {
        size_t gml = m0 + wm * 64 + mt * 16 + lhi * 4 + r;   // chunk-local row
        size_t gm = gml + (size_t)m_base;                     // global row
        int gn = n0 + wn * 64 + nt * 16 + l15;
        float v = acc[mt][nt][r] + bias[gn];
        if (EPI == EPI_QKV) {
          ((unsigned short*)out)[gml * (size_t)N + gn] = f2bf(v);
        } else if (EPI == EPI_MERGE) {
          int bi = (int)(gm >> 12), gg = (int)((gm >> 6) & 63), s = (int)(gm & 63);
          size_t sp = ((gg >> 3) * 8 + (s >> 3)) * 64 + (gg & 7) * 8 + (s & 7);
          v += ((const float*)res)[((size_t)(bi * 256 + gn)) * 4096 + sp];
          ((unsigned short*)out)[gm * 256 + gn] = f2bf(v);
        } else if (EPI == EPI_GELU) {
          float gl = 0.5f * v * (1.f + erff(v * 0.70710678118f));
          ((unsigned short*)out)[gml * (size_t)N + gn] = f2bf(gl);
        } else {  // EPI_OUT: + x2 residual, departition to [B,C,64,64] f32
          v += bf2f(((const unsigned short*)res)[gm * 256 + gn]);
          int bi = (int)(gm >> 12), gg = (int)((gm >> 6) & 63), s = (int)(gm & 63);
          size_t o = (size_t)(bi * 256 + gn) * 4096 +
                     ((gg >> 3) * 8 + (s >> 3)) * 64 + (gg & 7) * 8 + (s & 7);
          ((float*)out)[o] = v;
        }
      }
    }
  }
}

// ---- attention: one wave per (window, head) ----
__global__ __launch_bounds__(64) void attn_k(
    const unsigned short* __restrict__ qkv, const float* __restrict__ relb,
    unsigned short* __restrict__ o) {
  __shared__ __align__(16) unsigned short p_lds[64 * 72];
  __shared__ __align__(16) unsigned short vt_lds[32 * 72];
  const int l = threadIdx.x;
  const int l15 = l & 15, lhi = l >> 4;
  const int w = blockIdx.x, head = blockIdx.y;
  const unsigned short* base = qkv + (size_t)w * 64 * 768 + head * 32;

  short8 aq[4], bk[4];
#pragma unroll
  for (int t = 0; t < 4; t++) {
    aq[t] = *(const short8*)(base + (t * 16 + l15) * 768 + lhi * 8);
    bk[t] = *(const short8*)(base + 256 + (t * 16 + l15) * 768 + lhi * 8);
  }
  f32x4 s[4][4];
#pragma unroll
  for (int i = 0; i < 4; i++)
#pragma unroll
    for (int j = 0; j < 4; j++) s[i][j] = (f32x4){0.f, 0.f, 0.f, 0.f};
#pragma unroll
  for (int mt = 0; mt < 4; mt++)
#pragma unroll
    for (int nt = 0; nt < 4; nt++)
      s[mt][nt] = __builtin_amdgcn_mfma_f32_16x16x32_bf16(aq[mt], bk[nt], s[mt][nt], 0, 0, 0);

  const float* rb = relb + head * 4096;
  float rsum[4][4];
#pragma unroll
  for (int mt = 0; mt < 4; mt++) {
#pragma unroll
    for (int r = 0; r < 4; r++) {
      int row = mt * 16 + lhi * 4 + r;
      float vv[4];
      float vmax = -1e30f;
#pragma unroll
      for (int nt = 0; nt < 4; nt++) {
        int col = nt * 16 + l15;
        float v = s[mt][nt][r] * SCALE_F + rb[row * 64 + col];
        vv[nt] = v;
        vmax = fmaxf(vmax, v);
      }
#pragma unroll
      for (int d = 1; d < 16; d <<= 1) vmax = fmaxf(vmax, __shfl_xor(vmax, d, 64));
      float sum = 0.f;
#pragma unroll
      for (int nt = 0; nt < 4; nt++) {
        float p = __expf(vv[nt] - vmax);
        sum += p;
        p_lds[row * 72 + nt * 16 + l15] = f2bf(p);
      }
#pragma unroll
      for (int d = 1; d < 16; d <<= 1) sum += __shfl_xor(sum, d, 64);
      rsum[mt][r] = 1.f / sum;
    }
  }

  // stage v^T: vt[dh][token]
#pragma unroll
  for (int j = 0; j < 4; j++) {
    short8 vv = *(const short8*)(base + 512 + l * 768 + j * 8);
#pragma unroll
    for (int e = 0; e < 8; e++)
      vt_lds[(j * 8 + e) * 72 + l] = (unsigned short)vv[e];
  }
  __syncthreads();

  f32x4 o2[4][2];
#pragma unroll
  for (int i = 0; i < 4; i++) { o2[i][0] = (f32x4){0.f,0.f,0.f,0.f}; o2[i][1] = (f32x4){0.f,0.f,0.f,0.f}; }
#pragma unroll
  for (int ks = 0; ks < 2; ks++) {
    short8 ap[4], bv[2];
#pragma unroll
    for (int t = 0; t < 4; t++)
      ap[t] = *(const short8*)(&p_lds[(t * 16 + l15) * 72 + ks * 32 + lhi * 8]);
#pragma unroll
    for (int t = 0; t < 2; t++)
      bv[t] = *(const short8*)(&vt_lds[(t * 16 + l15) * 72 + ks * 32 + lhi * 8]);
#pragma unroll
    for (int mt = 0; mt < 4; mt++)
#pragma unroll
      for (int n2 = 0; n2 < 2; n2++)
        o2[mt][n2] = __builtin_amdgcn_mfma_f32_16x16x32_bf16(ap[mt], bv[n2], o2[mt][n2], 0, 0, 0);
  }
#pragma unroll
  for (int mt = 0; mt < 4; mt++)
#pragma unroll
    for (int n2 = 0; n2 < 2; n2++)
#pragma unroll
      for (int r = 0; r < 4; r++) {
        int row = mt * 16 + lhi * 4 + r;
        int dh = n2 * 16 + l15;
        o[((size_t)w * 64 + row) * 256 + head * 32 + dh] = f2bf(o2[mt][n2][r] * rsum[mt][r]);
      }
}

extern "C" void kernel_launch(void* const* d_in, const int* in_sizes, int n_in,
                              void* d_out, int out_size, void* d_ws, size_t ws_size,
                              hipStream_t stream) {
  (void)in_sizes; (void)n_in; (void)out_size;
  const float* x          = (const float*)d_in[0];
  const float* ln1_g      = (const float*)d_in[1];
  const float* ln1_b      = (const float*)d_in[2];
  const float* qkv_w      = (const float*)d_in[3];
  const float* qkv_b      = (const float*)d_in[4];
  const float* merge_w    = (const float*)d_in[5];
  const float* merge_b    = (const float*)d_in[6];
  const float* bias_table = (const float*)d_in[7];
  const float* ln2_g      = (const float*)d_in[8];
  const float* ln2_b      = (const float*)d_in[9];
  const float* mlp_w1     = (const float*)d_in[10];
  const float* mlp_b1     = (const float*)d_in[11];
  const float* mlp_w2     = (const float*)d_in[12];
  const float* mlp_b2     = (const float*)d_in[13];

  const size_t MB = 1024ull * 1024ull;
  char* ws = (char*)d_ws;
  // Fixed regions: 130 MiB total
  unsigned short* buf0 = (unsigned short*)(ws);             // 64 MiB: h -> attno -> h2
  unsigned short* x2   = (unsigned short*)(ws + 64 * MB);   // 64 MiB: bf16 residual-1 output
  unsigned short* wqkv = (unsigned short*)(ws + 128 * MB);  // [768][256] bf16
  unsigned short* wmrg = wqkv + 768 * 256;                  // [256][256]
  unsigned short* w1t  = wmrg + 256 * 256;                  // [1024][256]
  unsigned short* w2t  = w1t + 1024 * 256;                  // [256][1024]
  float* relb          = (float*)(w2t + 256 * 1024);        // [8][64][64] f32
  unsigned short* Cbuf = (unsigned short*)(ws + 130 * MB);  // adaptive scratch

  // Adaptive chunk sizes from ws_size (deterministic)
  size_t avail = ws_size > 130 * MB ? ws_size - 130 * MB : 0;
  int wc = 64;                                   // windows per qkv/attn chunk
  {
    const int cands[5] = {2048, 1024, 512, 256, 128};
    for (int i = 0; i < 5; i++)
      if ((size_t)cands[i] * 64 * 768 * 2 <= avail) { wc = cands[i]; break; }
  }
  int rc = 2048;                                 // rows per MLP chunk
  {
    const int cands[6] = {131072, 65536, 32768, 16384, 8192, 4096};
    for (int i = 0; i < 6; i++)
      if ((size_t)cands[i] * 1024 * 2 <= avail) { rc = cands[i]; break; }
  }

  cast_wt<256, 768><<<768, 256, 0, stream>>>(qkv_w, wqkv);
  cast_wt<256, 256><<<256, 256, 0, stream>>>(merge_w, wmrg);
  cast_wt<256, 1024><<<1024, 256, 0, stream>>>(mlp_w1, w1t);
  cast_wt<1024, 256><<<1024, 256, 0, stream>>>(mlp_w2, w2t);
  build_relb<<<128, 256, 0, stream>>>(bias_table, relb);

  part_ln1<<<32768, 256, 0, stream>>>(x, ln1_g, ln1_b, buf0);

  // QKV + attention, chunked over windows through Cbuf
  for (int w0 = 0; w0 < 2048; w0 += wc) {
    gemm_bt<EPI_QKV><<<dim3(wc * 64 / 128, 6), 256, 0, stream>>>(
        buf0 + (size_t)w0 * 64 * 256, wqkv, qkv_b, nullptr, Cbuf, 256, 768, 0);
    attn_k<<<dim3(wc, 8), 64, 0, stream>>>(Cbuf, relb, buf0 + (size_t)w0 * 64 * 256);
  }

  // merge projection + residual(x gather) -> x2 bf16
  gemm_bt<EPI_MERGE><<<dim3(1024, 2), 256, 0, stream>>>(
      buf0, wmrg, merge_b, x, x2, 256, 256, 0);

  ln2k<<<32768, 256, 0, stream>>>(x2, ln2_g, ln2_b, buf0);

  // MLP, chunked over rows through Cbuf
  for (long r0 = 0; r0 < 131072; r0 += rc) {
    gemm_bt<EPI_GELU><<<dim3(rc / 128, 8), 256, 0, stream>>>(
        buf0 + (size_t)r0 * 256, w1t, mlp_b1, nullptr, Cbuf, 256, 1024, 0);
    gemm_bt<EPI_OUT><<<dim3(rc / 128, 2), 256, 0, stream>>>(
        Cbuf, w2t, mlp_b2, x2, d_out, 1024, 256, r0);
  }
}